// Round 9
// baseline (370.495 us; speedup 1.0000x reference)
//
#include <hip/hip_runtime.h>
#include <hip/hip_bf16.h>
#include <stdint.h>

#define NROWS 32768
#define HDIM  1024
#define CNB   8
#define DCS   128
#define KCB   512
#define ROWS_PB 64

typedef short bf16x8 __attribute__((ext_vector_type(8)));
typedef float f32x4 __attribute__((ext_vector_type(4)));

__device__ __forceinline__ unsigned f2bfu(float x) {
  union { float f; unsigned u; } v; v.f = x;
  return (v.u + 0x7fffu + ((v.u >> 16) & 1u)) >> 16;
}
__device__ __forceinline__ float bfu2f(unsigned short b) {
  union { unsigned u; float f; } v; v.u = ((unsigned)b) << 16;
  return v.f;
}

// ---- prep: codesR[c][k][d] = bf16(codes[c][d][k] / ||code||)  (row-major, no swizzle)
//      cn2[c][k] = ||code||^2; zero loss slot.
__global__ __launch_bounds__(256) void prep_kernel(
    const float* __restrict__ codes, unsigned short* __restrict__ codesR,
    float* __restrict__ cn2, float* __restrict__ loss_slot) {
  const int c = blockIdx.y;
  const int k0 = blockIdx.x * 64;
  const int t = threadIdx.x;
  const int kl = t & 63;
  const int dq = t >> 6;
  const int k = k0 + kl;
  const float* src = codes + (size_t)c * DCS * KCB + k;
  float vbuf[32];
  float acc = 0.f;
#pragma unroll
  for (int i = 0; i < 32; ++i) {
    float v = src[(size_t)(dq * 32 + i) * KCB];
    vbuf[i] = v;
    acc += v * v;
  }
  __shared__ float red[256];
  red[t] = acc;
  __syncthreads();
  const float s = red[kl] + red[kl + 64] + red[kl + 128] + red[kl + 192];
  const float rn = rsqrtf(s);
  if (t < 64) cn2[c * KCB + k0 + t] = s;

  unsigned short* dst = codesR + ((size_t)c * KCB + k) * DCS + dq * 32;
#pragma unroll
  for (int g = 0; g < 4; ++g) {
    unsigned short pk[8];
#pragma unroll
    for (int j = 0; j < 8; ++j) pk[j] = (unsigned short)f2bfu(vbuf[g * 8 + j] * rn);
    *(uint4*)(dst + g * 8) = *(const uint4*)pk;
  }
  if (blockIdx.x == 0 && c == 0 && t == 0) *loss_slot = 0.f;
}

// ---- main: 64 rows x 1 codebook per block; 4 waves x 16 rows. NO LDS, NO BARRIERS.
// Codes read straight from L2 into registers, 2-deep pipelined with named reg sets.
__global__ __launch_bounds__(256, 4) void vq_kernel(
    const float* __restrict__ hidden, const float* __restrict__ gumbel,
    const unsigned short* __restrict__ codesR, const float* __restrict__ cn2g,
    float* __restrict__ out, float* __restrict__ loss_slot) {
  const int c = blockIdx.y;
  const int nb = blockIdx.x * ROWS_PB;
  const int tid = threadIdx.x;
  const int w = tid >> 6;
  const int l = tid & 63;
  const int l15 = l & 15;
  const int l4 = l >> 4;

  const char* cimg = (const char*)codesR + (size_t)c * (KCB * DCS * 2);  // 128 KB image
  const char* cfo = cimg + (l15 * 256 + l4 * 16);   // per-lane fragment base

  // --- h rows (issued first; their wait leaves tile-0 loads in flight)
  const int nrow = nb + w * 16 + l15;
  const float* hp = hidden + (size_t)nrow * HDIM + c * DCS + l4 * 8;
  f32x4 hr0[4], hr1[4];
#pragma unroll
  for (int s = 0; s < 4; ++s) {
    hr0[s] = *(const f32x4*)(hp + s * 32);
    hr1[s] = *(const f32x4*)(hp + s * 32 + 4);
  }

  const float* gb = gumbel + ((size_t)nrow * CNB + c) * KCB + l4 * 4;

  // --- tile-0 code+gumbel loads issued before the norm reduce (overlap)
  bf16x8 cA0, cA1, cA2, cA3, cB0, cB1, cB2, cB3;
  f32x4 gA, gB;
#define LOADT(C0, C1, C2, C3, G, T) { \
    const char* _p = cfo + (unsigned)(T) * 4096; \
    C0 = *(const bf16x8*)(_p); \
    C1 = *(const bf16x8*)(_p + 64); \
    C2 = *(const bf16x8*)(_p + 128); \
    C3 = *(const bf16x8*)(_p + 192); \
    G  = *(const f32x4*)(gb + (T) * 16); }

  LOADT(cA0, cA1, cA2, cA3, gA, 0)

  float hn2 = 0.f;
#pragma unroll
  for (int s = 0; s < 4; ++s)
#pragma unroll
    for (int j = 0; j < 4; ++j) hn2 += hr0[s][j] * hr0[s][j] + hr1[s][j] * hr1[s][j];
  hn2 += __shfl_xor(hn2, 16);
  hn2 += __shfl_xor(hn2, 32);
  const float hnorm = sqrtf(hn2);
  const float rh = hnorm > 0.f ? 1.0f / hnorm : 0.f;
  bf16x8 afr[4];
#pragma unroll
  for (int s = 0; s < 4; ++s)
#pragma unroll
    for (int j = 0; j < 4; ++j) {
      afr[s][j]     = (short)f2bfu(hr0[s][j] * rh);
      afr[s][4 + j] = (short)f2bfu(hr1[s][j] * rh);
    }

  float bs = -3.4e38f, ba = 0.f;
  int bk = 0;

#define STEP(C0, C1, C2, C3, G, T) { \
    f32x4 acc = (f32x4){0.f, 0.f, 0.f, 0.f}; \
    acc = __builtin_amdgcn_mfma_f32_16x16x32_bf16(C0, afr[0], acc, 0, 0, 0); \
    acc = __builtin_amdgcn_mfma_f32_16x16x32_bf16(C1, afr[1], acc, 0, 0, 0); \
    acc = __builtin_amdgcn_mfma_f32_16x16x32_bf16(C2, afr[2], acc, 0, 0, 0); \
    acc = __builtin_amdgcn_mfma_f32_16x16x32_bf16(C3, afr[3], acc, 0, 0, 0); \
    _Pragma("unroll") \
    for (int r = 0; r < 4; ++r) { \
      const float sc = acc[r] + G[r]; \
      const int kf = (T) * 16 + l4 * 4 + r; \
      if (sc > bs) { bs = sc; bk = kf; ba = acc[r]; } \
    } }

  // 2-deep pipeline over 32 tiles of 16 codes; zero barriers.
#pragma unroll 1
  for (int t = 0; t < 30; t += 2) {
    LOADT(cB0, cB1, cB2, cB3, gB, t + 1)
    STEP(cA0, cA1, cA2, cA3, gA, t)
    LOADT(cA0, cA1, cA2, cA3, gA, t + 2)
    STEP(cB0, cB1, cB2, cB3, gB, t + 1)
  }
  LOADT(cB0, cB1, cB2, cB3, gB, 31)
  STEP(cA0, cA1, cA2, cA3, gA, 30)
  STEP(cB0, cB1, cB2, cB3, gB, 31)
#undef LOADT
#undef STEP

  // --- cross-lane argmax over the 4 l4 replicas of each h-row
#pragma unroll
  for (int m = 16; m <= 32; m <<= 1) {
    float os = __shfl_xor(bs, m);
    int ok = __shfl_xor(bk, m);
    float oa = __shfl_xor(ba, m);
    if (os > bs || (os == bs && ok < bk)) { bs = os; bk = ok; ba = oa; }
  }

  // --- epilogue: nh = bf16(c/||c||) * ||c||; loss via ||c||^2+||h||^2-2*cos*||h||*||c||
  const float c2 = cn2g[c * KCB + bk];
  const float cn = sqrtf(c2);
  const float arg = c2 + hn2 - 2.f * (ba * hnorm * cn);
  float lsum = (l4 == 0) ? sqrtf(fmaxf(arg, 0.f)) : 0.f;

  const char* cb = cimg + (size_t)bk * 256;
  float* op = out + (size_t)nrow * HDIM + c * DCS + l4 * 32;
#pragma unroll
  for (int j = 0; j < 4; ++j) {
    bf16x8 cv = *(const bf16x8*)(cb + l4 * 64 + j * 16);
    f32x4 o0, o1;
#pragma unroll
    for (int e = 0; e < 4; ++e) {
      o0[e] = bfu2f((unsigned short)cv[e]) * cn;
      o1[e] = bfu2f((unsigned short)cv[4 + e]) * cn;
    }
    *(f32x4*)(op + j * 8) = o0;
    *(f32x4*)(op + j * 8 + 4) = o1;
  }

  // --- per-wave loss reduce + one atomic per wave
#pragma unroll
  for (int m = 1; m <= 32; m <<= 1) lsum += __shfl_xor(lsum, m);
  if (l == 0) atomicAdd(loss_slot, lsum * 1.2f);
}

extern "C" void kernel_launch(void* const* d_in, const int* in_sizes, int n_in,
                              void* d_out, int out_size, void* d_ws, size_t ws_size,
                              hipStream_t stream) {
  const float* hidden = (const float*)d_in[0];
  const float* codes  = (const float*)d_in[1];
  const float* gumbel = (const float*)d_in[2];
  float* out = (float*)d_out;
  unsigned short* codesR = (unsigned short*)d_ws;              // 2 MB (8 x 128KB images)
  float* cn2 = (float*)((char*)d_ws + (size_t)CNB * KCB * DCS * 2);  // 16 KB
  float* loss_slot = out + (size_t)NROWS * HDIM;

  prep_kernel<<<dim3(8, CNB), 256, 0, stream>>>(codes, codesR, cn2, loss_slot);
  vq_kernel<<<dim3(NROWS / ROWS_PB, CNB), 256, 0, stream>>>(hidden, gumbel, codesR, cn2, out, loss_slot);
}

// Round 10
// 369.265 us; speedup vs baseline: 1.0033x; 1.0033x over previous
//
#include <hip/hip_runtime.h>
#include <hip/hip_bf16.h>
#include <stdint.h>

#define NROWS 32768
#define HDIM  1024
#define CNB   8
#define DCS   128
#define KCB   512
#define ROWS_PB 64

typedef short bf16x8 __attribute__((ext_vector_type(8)));
typedef float f32x4 __attribute__((ext_vector_type(4)));

__device__ __forceinline__ unsigned f2bfu(float x) {
  union { float f; unsigned u; } v; v.f = x;
  return (v.u + 0x7fffu + ((v.u >> 16) & 1u)) >> 16;
}
__device__ __forceinline__ float bfu2f(unsigned short b) {
  union { unsigned u; float f; } v; v.u = ((unsigned)b) << 16;
  return v.f;
}

// ---- prep: codesR[c][k][d] = bf16(codes[c][d][k] / ||code||)  (row-major)
//      cn2[c][k] = ||code||^2; zero loss slot.
__global__ __launch_bounds__(256) void prep_kernel(
    const float* __restrict__ codes, unsigned short* __restrict__ codesR,
    float* __restrict__ cn2, float* __restrict__ loss_slot) {
  const int c = blockIdx.y;
  const int k0 = blockIdx.x * 64;
  const int t = threadIdx.x;
  const int kl = t & 63;
  const int dq = t >> 6;
  const int k = k0 + kl;
  const float* src = codes + (size_t)c * DCS * KCB + k;
  float vbuf[32];
  float acc = 0.f;
#pragma unroll
  for (int i = 0; i < 32; ++i) {
    float v = src[(size_t)(dq * 32 + i) * KCB];
    vbuf[i] = v;
    acc += v * v;
  }
  __shared__ float red[256];
  red[t] = acc;
  __syncthreads();
  const float s = red[kl] + red[kl + 64] + red[kl + 128] + red[kl + 192];
  const float rn = rsqrtf(s);
  if (t < 64) cn2[c * KCB + k0 + t] = s;

  unsigned short* dst = codesR + ((size_t)c * KCB + k) * DCS + dq * 32;
#pragma unroll
  for (int g = 0; g < 4; ++g) {
    unsigned short pk[8];
#pragma unroll
    for (int j = 0; j < 8; ++j) pk[j] = (unsigned short)f2bfu(vbuf[g * 8 + j] * rn);
    *(uint4*)(dst + g * 8) = *(const uint4*)pk;
  }
  if (blockIdx.x == 0 && c == 0 && t == 0) *loss_slot = 0.f;
}

// ---- main: 64 rows x 1 codebook per block; 4 waves x 16 rows. NO LDS, NO BARRIERS.
// 4 groups x 8 tiles; gumbel for group g+1 issued at start of group g (deep prefetch);
// code tiles from L2, 2-deep pipelined. Fully unrolled -> constant reg indices.
__global__ __launch_bounds__(256) void vq_kernel(
    const float* __restrict__ hidden, const float* __restrict__ gumbel,
    const unsigned short* __restrict__ codesR, const float* __restrict__ cn2g,
    float* __restrict__ out, float* __restrict__ loss_slot) {
  const int c = blockIdx.y;
  const int nb = blockIdx.x * ROWS_PB;
  const int tid = threadIdx.x;
  const int w = tid >> 6;
  const int l = tid & 63;
  const int l15 = l & 15;
  const int l4 = l >> 4;

  const char* cimg = (const char*)codesR + (size_t)c * (KCB * DCS * 2);  // 128 KB image
  const char* cfo = cimg + (l15 * 256 + l4 * 16);   // per-lane A-fragment base

  // --- h rows (issued first; in-order vmcnt lets us wait on these without draining later loads)
  const int nrow = nb + w * 16 + l15;
  const float* hp = hidden + (size_t)nrow * HDIM + c * DCS + l4 * 8;
  f32x4 hr0[4], hr1[4];
#pragma unroll
  for (int s = 0; s < 4; ++s) {
    hr0[s] = *(const f32x4*)(hp + s * 32);
    hr1[s] = *(const f32x4*)(hp + s * 32 + 4);
  }

  const float* gb = gumbel + ((size_t)nrow * CNB + c) * KCB + l4 * 4;

  f32x4 gq[2][8];     // gumbel, 2 groups deep (constant-indexed only)
  bf16x8 cf[2][4];    // code tiles, 2 deep (constant-indexed only)

  // group-0 gumbel + tile-0 codes issued before the norm reduce (overlap)
#pragma unroll
  for (int t = 0; t < 8; ++t) gq[0][t] = *(const f32x4*)(gb + t * 16);
#pragma unroll
  for (int s = 0; s < 4; ++s) cf[0][s] = *(const bf16x8*)(cfo + s * 64);

  float hn2 = 0.f;
#pragma unroll
  for (int s = 0; s < 4; ++s)
#pragma unroll
    for (int j = 0; j < 4; ++j) hn2 += hr0[s][j] * hr0[s][j] + hr1[s][j] * hr1[s][j];
  hn2 += __shfl_xor(hn2, 16);
  hn2 += __shfl_xor(hn2, 32);
  const float hnorm = sqrtf(hn2);
  const float rh = hnorm > 0.f ? 1.0f / hnorm : 0.f;
  bf16x8 afr[4];
#pragma unroll
  for (int s = 0; s < 4; ++s)
#pragma unroll
    for (int j = 0; j < 4; ++j) {
      afr[s][j]     = (short)f2bfu(hr0[s][j] * rh);
      afr[s][4 + j] = (short)f2bfu(hr1[s][j] * rh);
    }

  float bs = -3.4e38f, ba = 0.f;
  int bk = 0;

  // 4 groups x 8 tiles, fully unrolled
#pragma unroll
  for (int g = 0; g < 4; ++g) {
    // deep prefetch: next group's gumbel (consumed ~8 STEPs from now)
    if (g < 3) {
#pragma unroll
      for (int t = 0; t < 8; ++t)
        gq[(g + 1) & 1][t] = *(const f32x4*)(gb + (g + 1) * 128 + t * 16);
    }
#pragma unroll
    for (int t = 0; t < 8; ++t) {
      const int tile = g * 8 + t;
      // 2-deep code prefetch
      if (tile + 1 < 32) {
        const char* _p = cfo + (unsigned)(tile + 1) * 4096;
#pragma unroll
        for (int s = 0; s < 4; ++s) cf[(t + 1) & 1][s] = *(const bf16x8*)(_p + s * 64);
      }
      f32x4 acc = (f32x4){0.f, 0.f, 0.f, 0.f};
      acc = __builtin_amdgcn_mfma_f32_16x16x32_bf16(cf[t & 1][0], afr[0], acc, 0, 0, 0);
      acc = __builtin_amdgcn_mfma_f32_16x16x32_bf16(cf[t & 1][1], afr[1], acc, 0, 0, 0);
      acc = __builtin_amdgcn_mfma_f32_16x16x32_bf16(cf[t & 1][2], afr[2], acc, 0, 0, 0);
      acc = __builtin_amdgcn_mfma_f32_16x16x32_bf16(cf[t & 1][3], afr[3], acc, 0, 0, 0);
#pragma unroll
      for (int r = 0; r < 4; ++r) {
        const float sc = acc[r] + gq[g & 1][t][r];
        const int kf = tile * 16 + l4 * 4 + r;
        if (sc > bs) { bs = sc; bk = kf; ba = acc[r]; }
      }
    }
  }

  // --- cross-lane argmax over the 4 l4 replicas of each h-row
#pragma unroll
  for (int m = 16; m <= 32; m <<= 1) {
    float os = __shfl_xor(bs, m);
    int ok = __shfl_xor(bk, m);
    float oa = __shfl_xor(ba, m);
    if (os > bs || (os == bs && ok < bk)) { bs = os; bk = ok; ba = oa; }
  }

  // --- epilogue: nh = bf16(c/||c||) * ||c||; loss via ||c||^2+||h||^2-2*cos*||h||*||c||
  const float c2 = cn2g[c * KCB + bk];
  const float cn = sqrtf(c2);
  const float arg = c2 + hn2 - 2.f * (ba * hnorm * cn);
  float lsum = (l4 == 0) ? sqrtf(fmaxf(arg, 0.f)) : 0.f;

  const char* cb = cimg + (size_t)bk * 256;
  float* op = out + (size_t)nrow * HDIM + c * DCS + l4 * 32;
#pragma unroll
  for (int j = 0; j < 4; ++j) {
    bf16x8 cv = *(const bf16x8*)(cb + l4 * 64 + j * 16);
    f32x4 o0, o1;
#pragma unroll
    for (int e = 0; e < 4; ++e) {
      o0[e] = bfu2f((unsigned short)cv[e]) * cn;
      o1[e] = bfu2f((unsigned short)cv[4 + e]) * cn;
    }
    *(f32x4*)(op + j * 8) = o0;
    *(f32x4*)(op + j * 8 + 4) = o1;
  }

  // --- per-wave loss reduce + one atomic per wave
#pragma unroll
  for (int m = 1; m <= 32; m <<= 1) lsum += __shfl_xor(lsum, m);
  if (l == 0) atomicAdd(loss_slot, lsum * 1.2f);
}

extern "C" void kernel_launch(void* const* d_in, const int* in_sizes, int n_in,
                              void* d_out, int out_size, void* d_ws, size_t ws_size,
                              hipStream_t stream) {
  const float* hidden = (const float*)d_in[0];
  const float* codes  = (const float*)d_in[1];
  const float* gumbel = (const float*)d_in[2];
  float* out = (float*)d_out;
  unsigned short* codesR = (unsigned short*)d_ws;              // 2 MB (8 x 128KB images)
  float* cn2 = (float*)((char*)d_ws + (size_t)CNB * KCB * DCS * 2);  // 16 KB
  float* loss_slot = out + (size_t)NROWS * HDIM;

  prep_kernel<<<dim3(8, CNB), 256, 0, stream>>>(codes, codesR, cn2, loss_slot);
  vq_kernel<<<dim3(NROWS / ROWS_PB, CNB), 256, 0, stream>>>(hidden, gumbel, codesR, cn2, out, loss_slot);
}

// Round 11
// 281.312 us; speedup vs baseline: 1.3170x; 1.3127x over previous
//
#include <hip/hip_runtime.h>
#include <hip/hip_bf16.h>
#include <stdint.h>

#define NROWS 32768
#define HDIM  1024
#define CNB   8
#define DCS   128
#define KCB   512
#define ROWS_PB 128

typedef short bf16x8 __attribute__((ext_vector_type(8)));
typedef float f32x4 __attribute__((ext_vector_type(4)));

__device__ __forceinline__ unsigned f2bfu(float x) {
  union { float f; unsigned u; } v; v.f = x;
  return (v.u + 0x7fffu + ((v.u >> 16) & 1u)) >> 16;
}
__device__ __forceinline__ float bfu2f(unsigned short b) {
  union { unsigned u; float f; } v; v.u = ((unsigned)b) << 16;
  return v.f;
}
__device__ __forceinline__ void gload_lds16(const void* g, void* l) {
  __builtin_amdgcn_global_load_lds(
      (const __attribute__((address_space(1))) uint32_t*)g,
      (__attribute__((address_space(3))) uint32_t*)l, 16, 0, 0);
}

// ---- prep: codesB[c] = bf16 image of codes PRE-SCALED by 1/||code||, XOR-swizzled,
//      4 chunks x 32KB per codebook, gl_lds-ready. cn2[c][k] = ||code||^2; zero loss.
// image byte for (k,d): (k>>7)*32768 + (k&127)*256 + ((2d) ^ ((k&7)<<4))
__global__ __launch_bounds__(256) void prep_kernel(
    const float* __restrict__ codes, unsigned short* __restrict__ codesB,
    float* __restrict__ cn2, float* __restrict__ loss_slot) {
  const int c = blockIdx.y;
  const int k0 = blockIdx.x * 64;
  const int t = threadIdx.x;
  const int kl = t & 63;
  const int dq = t >> 6;
  const int k = k0 + kl;
  const float* src = codes + (size_t)c * DCS * KCB + k;
  float vbuf[32];
  float acc = 0.f;
#pragma unroll
  for (int i = 0; i < 32; ++i) {
    float v = src[(size_t)(dq * 32 + i) * KCB];
    vbuf[i] = v;
    acc += v * v;
  }
  __shared__ float red[256];
  red[t] = acc;
  __syncthreads();
  const float s = red[kl] + red[kl + 64] + red[kl + 128] + red[kl + 192];
  const float rn = rsqrtf(s);
  if (t < 64) cn2[c * KCB + k0 + t] = s;

  char* dstbase = (char*)codesB + (size_t)c * 131072 + (size_t)(k >> 7) * 32768 + (k & 127) * 256;
  const unsigned swzk = (unsigned)(k & 7) << 4;
#pragma unroll
  for (int g = 0; g < 4; ++g) {
    unsigned short pk[8];
#pragma unroll
    for (int j = 0; j < 8; ++j) pk[j] = (unsigned short)f2bfu(vbuf[g * 8 + j] * rn);
    unsigned d2 = (unsigned)((dq * 32 + g * 8) * 2);
    *(uint4*)(dstbase + (d2 ^ swzk)) = *(const uint4*)pk;
  }
  if (blockIdx.x == 0 && c == 0 && t == 0) *loss_slot = 0.f;
}

// ---- main: 128 rows x 1 codebook per block; 8 waves x 16 rows.
// r6 structure but with raw s_barrier (NO vmcnt(0) drains in the loop).
// Correctness via in-order vmcnt retirement: STAGE(i+2) issued BEFORE gumbel(i+1),
// so the score phase's counted wait on gumbel(i) implies stage(i+1) is retired.
__global__ __launch_bounds__(512, 4) void vq_kernel(
    const float* __restrict__ hidden, const float* __restrict__ gumbel,
    const unsigned short* __restrict__ codesB, const float* __restrict__ cn2g,
    float* __restrict__ out, float* __restrict__ loss_slot) {
  const int c = blockIdx.y;
  const int nb = blockIdx.x * ROWS_PB;
  const int tid = threadIdx.x;
  const int w = tid >> 6;
  const int l = tid & 63;
  const int l15 = l & 15;
  const int l4 = l >> 4;

  __shared__ char ldsB[2 * 32768];   // 2 x 32KB chunk: [k_local 128][d 128] bf16, swizzled

  const char* cbase = (const char*)codesB + (size_t)c * 131072;

#define STAGE(chunk) { \
    const char* _s = cbase + (size_t)(chunk) * 32768; \
    char* _d = ldsB + ((chunk) & 1) * 32768 + w * 1024; \
    gload_lds16(_s + 0 * 8192 + tid * 16, _d + 0 * 8192); \
    gload_lds16(_s + 1 * 8192 + tid * 16, _d + 1 * 8192); \
    gload_lds16(_s + 2 * 8192 + tid * 16, _d + 2 * 8192); \
    gload_lds16(_s + 3 * 8192 + tid * 16, _d + 3 * 8192); }

  // --- h rows (issued first = oldest in vmcnt queue)
  const int nrow = nb + w * 16 + l15;
  const float* hp = hidden + (size_t)nrow * HDIM + c * DCS + l4 * 8;
  f32x4 hr0[4], hr1[4];
#pragma unroll
  for (int s = 0; s < 4; ++s) {
    hr0[s] = *(const f32x4*)(hp + s * 32);
    hr1[s] = *(const f32x4*)(hp + s * 32 + 4);
  }
  __builtin_amdgcn_sched_barrier(0);

  // prologue: stage chunks 0,1 THEN gumbel(0) (order matters for the invariant)
  STAGE(0)
  STAGE(1)
  __builtin_amdgcn_sched_barrier(0);

  const float* gb = gumbel + ((size_t)nrow * CNB + c) * KCB + l4 * 4;
  f32x4 g0[8], g1[8];
#pragma unroll
  for (int t = 0; t < 8; ++t) g0[t] = *(const f32x4*)(gb + t * 16);
  __builtin_amdgcn_sched_barrier(0);

  // --- norm + bf16 A-fragments (hides h-load wait; stages/gumbel stay in flight)
  float hn2 = 0.f;
#pragma unroll
  for (int s = 0; s < 4; ++s)
#pragma unroll
    for (int j = 0; j < 4; ++j) hn2 += hr0[s][j] * hr0[s][j] + hr1[s][j] * hr1[s][j];
  hn2 += __shfl_xor(hn2, 16);
  hn2 += __shfl_xor(hn2, 32);
  const float hnorm = sqrtf(hn2);
  const float rh = hnorm > 0.f ? 1.0f / hnorm : 0.f;
  bf16x8 afr[4];
#pragma unroll
  for (int s = 0; s < 4; ++s)
#pragma unroll
    for (int j = 0; j < 4; ++j) {
      afr[s][j]     = (short)f2bfu(hr0[s][j] * rh);
      afr[s][4 + j] = (short)f2bfu(hr1[s][j] * rh);
    }

  const unsigned swz = (unsigned)(l15 & 7) << 4;
  float bs = -3.4e38f, ba = 0.f;
  int bk = 0;

  __syncthreads();   // ONE full drain: chunks 0,1 + g0 ready. Loop has no drains.

  // Per iteration I: STAGE(I+2) -> gumbel(I+1) prefetch -> MFMA+score on buf[I&1]
  // -> raw s_barrier. sched_barrier(0) pins phase order so in-order vmcnt
  // retirement guarantees stage(I+1) done before iter I+1 reads it.
#define ITER(I, GC, GN) { \
    if ((I) < 2) STAGE((I) + 2) \
    __builtin_amdgcn_sched_barrier(0); \
    if ((I) < 3) { \
      _Pragma("unroll") \
      for (int t = 0; t < 8; ++t) GN[t] = *(const f32x4*)(gb + ((I) + 1) * 128 + t * 16); \
    } \
    __builtin_amdgcn_sched_barrier(0); \
    const char* buf = ldsB + ((I) & 1) * 32768; \
    _Pragma("unroll") \
    for (int t = 0; t < 8; ++t) { \
      const unsigned rowbase = (unsigned)((t * 16 + l15) * 256); \
      f32x4 acc = (f32x4){0.f, 0.f, 0.f, 0.f}; \
      _Pragma("unroll") \
      for (int s = 0; s < 4; ++s) { \
        bf16x8 bfr = *(const bf16x8*)(buf + rowbase + (((unsigned)(s * 64 + l4 * 16)) ^ swz)); \
        acc = __builtin_amdgcn_mfma_f32_16x16x32_bf16(bfr, afr[s], acc, 0, 0, 0); \
      } \
      _Pragma("unroll") \
      for (int r = 0; r < 4; ++r) { \
        const float sc = acc[r] + GC[t][r]; \
        const int kf = (I) * 128 + t * 16 + l4 * 4 + r; \
        if (sc > bs) { bs = sc; bk = kf; ba = acc[r]; } \
      } \
    } \
    __builtin_amdgcn_sched_barrier(0); \
    if ((I) < 3) __builtin_amdgcn_s_barrier(); \
    __builtin_amdgcn_sched_barrier(0); }

  ITER(0, g0, g1)
  ITER(1, g1, g0)
  ITER(2, g0, g1)
  ITER(3, g1, g0)
#undef ITER
#undef STAGE

  // --- cross-lane argmax over the 4 l4 replicas of each h-row
#pragma unroll
  for (int m = 16; m <= 32; m <<= 1) {
    float os = __shfl_xor(bs, m);
    int ok = __shfl_xor(bk, m);
    float oa = __shfl_xor(ba, m);
    if (os > bs || (os == bs && ok < bk)) { bs = os; bk = ok; ba = oa; }
  }

  // --- epilogue: nh = bf16(c/||c||) * ||c||; loss via ||c||^2+||h||^2-2*cos*||h||*||c||
  const float c2 = cn2g[c * KCB + bk];
  const float cn = sqrtf(c2);
  const float arg = c2 + hn2 - 2.f * (ba * hnorm * cn);
  float lsum = (l4 == 0) ? sqrtf(fmaxf(arg, 0.f)) : 0.f;

  const char* cb = cbase + (size_t)(bk >> 7) * 32768 + (bk & 127) * 256;
  const unsigned swzk = (unsigned)(bk & 7) << 4;
  float* op = out + (size_t)nrow * HDIM + c * DCS + l4 * 32;
#pragma unroll
  for (int j = 0; j < 4; ++j) {
    unsigned d2 = (unsigned)((l4 * 32 + j * 8) * 2);
    bf16x8 cv = *(const bf16x8*)(cb + (d2 ^ swzk));
    f32x4 o0, o1;
#pragma unroll
    for (int e = 0; e < 4; ++e) {
      o0[e] = bfu2f((unsigned short)cv[e]) * cn;
      o1[e] = bfu2f((unsigned short)cv[4 + e]) * cn;
    }
    *(f32x4*)(op + j * 8) = o0;
    *(f32x4*)(op + j * 8 + 4) = o1;
  }

  // --- per-wave loss reduce + one atomic per wave
#pragma unroll
  for (int m = 1; m <= 32; m <<= 1) lsum += __shfl_xor(lsum, m);
  if (l == 0) atomicAdd(loss_slot, lsum * 1.2f);
}

extern "C" void kernel_launch(void* const* d_in, const int* in_sizes, int n_in,
                              void* d_out, int out_size, void* d_ws, size_t ws_size,
                              hipStream_t stream) {
  const float* hidden = (const float*)d_in[0];
  const float* codes  = (const float*)d_in[1];
  const float* gumbel = (const float*)d_in[2];
  float* out = (float*)d_out;
  unsigned short* codesB = (unsigned short*)d_ws;              // 1 MB (8 x 128KB images)
  float* cn2 = (float*)((char*)d_ws + (size_t)CNB * 131072);   // 16 KB
  float* loss_slot = out + (size_t)NROWS * HDIM;

  prep_kernel<<<dim3(8, CNB), 256, 0, stream>>>(codes, codesB, cn2, loss_slot);
  vq_kernel<<<dim3(NROWS / ROWS_PB, CNB), 512, 0, stream>>>(hidden, gumbel, codesB, cn2, out, loss_slot);
}